// Round 3
// baseline (171.887 us; speedup 1.0000x reference)
//
#include <hip/hip_runtime.h>

// Updater: B=4194304 sequential scan, 3 independent scalar recurrences
//   net' = sigmoid(10*(net + u - 0.5)), u = W*x + b, pred = x . net'
// Chunked-scan parallelization with certified warm-up (monotone map ->
// trajectories from 0 and 1 bracket the truth; dual-trajectory warm-up with
// wave-uniform early exit; geometric global backoff, rare, exact at net0).
//
// R3 vs R2 (~31us kernel): occupancy was GRID-limited at CHUNK=16
// (4096 waves = 4/SIMD) and ~70% of cycles were stalls (74k cy/SIMD vs
// ~21k issue estimate). Changes:
//  - CHUNK=8 -> 2048 blocks, 8192 waves = 8 waves/SIMD, IF VGPR<=64
//    (forced via __launch_bounds__(256,8); live set ~55-60 regs).
//  - Warm fetches batched 4 steps at a time: 12 bpermutes + masked
//    boundary LDS reads, ~1 lgkm wait per 4 steps (was per-step).
//  - block0/wave0 "exact" lanes moved to a rolled slow path taken by ONE
//    wave in the grid (global x reads) -> no per-step predication and
//    half the warm code for all other waves.
//  - EPS 1e-6 -> 1e-5 (pred error contribution ~5e-5 << 0.0156 margin).

#if __has_builtin(__builtin_amdgcn_exp2f)
#define EXP2F(v) __builtin_amdgcn_exp2f(v)
#else
#define EXP2F(v) __expf(0.6931471805599453f * (v))
#endif

namespace {
constexpr int   BTOT   = 4194304;
constexpr int   CHUNK  = 8;                   // output steps per thread
constexpr int   BLOCK  = 256;
constexpr int   BSTEPS = BLOCK * CHUNK;       // 2048 steps per block
constexpr int   WARM   = 32;                  // warm-up window (steps)
constexpr int   GRID   = BTOT / BSTEPS;       // 2048 blocks
constexpr float KEXP   = -14.426950408889634f; // -10 * log2(e)
constexpr float EPS    = 1e-5f;
}

// sigmoid(10*(n+u-0.5)) = rcp(1 + exp2(KEXP*n + c)), c = (KEXP*W)x + KEXP*(b-.5)
#define CVALS(X0_, X1_, X2_)                                                   \
  const float c0 = fmaf(kw00, (X0_), fmaf(kw01, (X1_), fmaf(kw02, (X2_), kb0))); \
  const float c1 = fmaf(kw10, (X0_), fmaf(kw11, (X1_), fmaf(kw12, (X2_), kb1))); \
  const float c2 = fmaf(kw20, (X0_), fmaf(kw21, (X1_), fmaf(kw22, (X2_), kb2)));

#define SIG(N, C) __builtin_amdgcn_rcpf(1.0f + EXP2F(fmaf(KEXP, (N), (C))))

// lane-pull: value of (lane - d), d preencoded as byte addr
#define PULL(VAL_, AD_)                                                        \
  __int_as_float(__builtin_amdgcn_ds_bpermute((AD_), __float_as_int(VAL_)))

// fetch warm-step S_'s x. Owner lane = lane - (4 - (S_>>3)); boundary lanes
// (8*lane + S_ < 32, exactly the invalid-pull set) read the per-wave LDS
// window instead.
#define FETCH1(S_, XD0, XD1, XD2, AD_)                                         \
  XD0 = PULL(fx[3 * ((S_) & 7) + 0], AD_);                                     \
  XD1 = PULL(fx[3 * ((S_) & 7) + 1], AD_);                                     \
  XD2 = PULL(fx[3 * ((S_) & 7) + 2], AD_);                                     \
  if (8 * lane + (S_) < WARM) {                                                \
    const float4 wv_ = wbuf[w][8 * lane + (S_)];                               \
    XD0 = wv_.x; XD1 = wv_.y; XD2 = wv_.z;                                     \
  }

// dual-trajectory (bracket) step
#define DSTEP(X0_, X1_, X2_)                                                   \
  {                                                                            \
    CVALS(X0_, X1_, X2_)                                                       \
    lo0 = SIG(lo0, c0); hi0 = SIG(hi0, c0);                                    \
    lo1 = SIG(lo1, c1); hi1 = SIG(hi1, c1);                                    \
    lo2 = SIG(lo2, c2); hi2 = SIG(hi2, c2);                                    \
  }

// single-trajectory step
#define SSTEP(X0_, X1_, X2_)                                                   \
  {                                                                            \
    CVALS(X0_, X1_, X2_)                                                       \
    m0 = SIG(m0, c0); m1 = SIG(m1, c1); m2 = SIG(m2, c2);                      \
  }

// warm batch: 4 steps, fetches hoisted above the uniform dual/single branch
#define WBATCH(B_, AD_)                                                        \
  {                                                                            \
    float X00,X01,X02,X10,X11,X12,X20,X21,X22,X30,X31,X32;                     \
    FETCH1(4*(B_)+0, X00, X01, X02, AD_)                                       \
    FETCH1(4*(B_)+1, X10, X11, X12, AD_)                                       \
    FETCH1(4*(B_)+2, X20, X21, X22, AD_)                                       \
    FETCH1(4*(B_)+3, X30, X31, X32, AD_)                                       \
    if (!single) {                                                             \
      DSTEP(X00, X01, X02) DSTEP(X10, X11, X12)                                \
      DSTEP(X20, X21, X22) DSTEP(X30, X31, X32)                                \
      conv = ((hi0 - lo0) < EPS) & ((hi1 - lo1) < EPS) & ((hi2 - lo2) < EPS);  \
      if (__all(conv)) {                                                       \
        m0 = 0.5f * (lo0 + hi0); m1 = 0.5f * (lo1 + hi1);                      \
        m2 = 0.5f * (lo2 + hi2);                                               \
        single = true;                                                         \
      }                                                                        \
    } else {                                                                   \
      SSTEP(X00, X01, X02) SSTEP(X10, X11, X12)                                \
      SSTEP(X20, X21, X22) SSTEP(X30, X31, X32)                                \
    }                                                                          \
  }

// main step: advance + pred (x from registers)
#define MS(P_, X0_, X1_, X2_)                                                  \
  {                                                                            \
    CVALS(X0_, X1_, X2_)                                                       \
    m0 = SIG(m0, c0); m1 = SIG(m1, c1); m2 = SIG(m2, c2);                      \
    P_ = fmaf((X0_), m0, fmaf((X1_), m1, (X2_) * m2));                         \
  }

__global__ __launch_bounds__(BLOCK, 8) void Updater_65395172049297_kernel(
    const float* __restrict__ x, const float* __restrict__ W,
    const float* __restrict__ bv, const float* __restrict__ n0v,
    float* __restrict__ out)
{
    __shared__ float4 wbuf[BLOCK / 64][WARM];   // 4 waves x 32 steps = 2KB

    const float kw00 = KEXP * W[0], kw01 = KEXP * W[1], kw02 = KEXP * W[2];
    const float kw10 = KEXP * W[3], kw11 = KEXP * W[4], kw12 = KEXP * W[5];
    const float kw20 = KEXP * W[6], kw21 = KEXP * W[7], kw22 = KEXP * W[8];
    const float kb0 = KEXP * (bv[0] - 0.5f);
    const float kb1 = KEXP * (bv[1] - 0.5f);
    const float kb2 = KEXP * (bv[2] - 0.5f);
    const float n00 = n0v[0], n01 = n0v[1], n02 = n0v[2];

    const int  lane  = threadIdx.x & 63;
    const int  w     = threadIdx.x >> 6;
    const long S     = (long)blockIdx.x * BSTEPS;
    const long start = S + (long)threadIdx.x * CHUNK;

    // bpermute byte addresses for lane-d pulls (clamped; invalid pulls are
    // exactly the LDS-boundary lanes, which overwrite)
    const int a1 = ((lane >= 1) ? (lane - 1) : lane) << 2;
    const int a2 = ((lane >= 2) ? (lane - 2) : lane) << 2;
    const int a3 = ((lane >= 3) ? (lane - 3) : lane) << 2;
    const int a4 = ((lane >= 4) ? (lane - 4) : lane) << 2;

    // ---- one-shot gather: this thread's 8-step x chunk into registers ----
    float fx[24];
    {
        const float4* mp = reinterpret_cast<const float4*>(x + 3 * start);
#pragma unroll
        for (int i = 0; i < 6; ++i) {
            const float4 v = mp[i];
            fx[4 * i + 0] = v.x; fx[4 * i + 1] = v.y;
            fx[4 * i + 2] = v.z; fx[4 * i + 3] = v.w;
        }
    }

    // ---- stage per-wave boundary window (32 steps before wave start) ----
    {
        const long wbase = S + (long)w * (64 * CHUNK);
        if (lane < WARM) {
            long sstep = wbase - WARM + lane;
            if (sstep < 0) sstep = 0;   // block0/wave0: never consumed
            const float* xp = x + 3 * sstep;
            wbuf[w][lane] = make_float4(xp[0], xp[1], xp[2], 0.0f);
        }
    }
    __syncthreads();

    const bool exact   = (start <= (long)WARM);          // block0/wave0 lanes 0..4
    const int  smin    = exact ? (int)(WARM - (int)start) : 0;
    const bool special = (blockIdx.x == 0) && (w == 0);

    float lo0, lo1, lo2, hi0, hi1, hi2;
    if (exact) { lo0 = hi0 = n00; lo1 = hi1 = n01; lo2 = hi2 = n02; }
    else       { lo0 = lo1 = lo2 = 0.0f; hi0 = hi1 = hi2 = 1.0f; }

    bool  conv = false, single = false;
    float m0 = n00, m1 = n01, m2 = n02;

    if (special) {
        // ONE wave in the grid: rolled warm-up straight from global x.
        // Exact lanes (lo==hi==net0) skip steps < smin; conv trivially true.
        for (int s = 0; s < WARM; ++s) {
            if (s >= smin) {
                const long as_ = start - WARM + s;   // >= 0 here
                const float X0 = x[3 * as_], X1 = x[3 * as_ + 1], X2 = x[3 * as_ + 2];
                DSTEP(X0, X1, X2)
            }
        }
        conv = ((hi0 - lo0) < EPS) & ((hi1 - lo1) < EPS) & ((hi2 - lo2) < EPS);
        if (__all(conv)) {
            m0 = 0.5f * (lo0 + hi0); m1 = 0.5f * (lo1 + hi1); m2 = 0.5f * (lo2 + hi2);
            single = true;
        }
    } else {
        // fast path: 8 batches of 4 steps; owner distance d = 4 - (S>>3)
        WBATCH(0, a4) WBATCH(1, a4)
        WBATCH(2, a3) WBATCH(3, a3)
        WBATCH(4, a2) WBATCH(5, a2)
        WBATCH(6, a1) WBATCH(7, a1)
    }

    if (!single) {
        // rare certified backoff: extend window 4x per attempt (global x)
        for (int at = 1; at < 10 && !conv; ++at) {
            long wl2 = (long)WARM << (2 * at);
            long bgn = start - wl2;
            bool ex2 = (bgn <= 0);
            if (ex2) bgn = 0;
            if (ex2) { lo0 = hi0 = n00; lo1 = hi1 = n01; lo2 = hi2 = n02; }
            else     { lo0 = lo1 = lo2 = 0.0f; hi0 = hi1 = hi2 = 1.0f; }
            const float4* bp = reinterpret_cast<const float4*>(x + 3 * bgn);
            const long ng = (start - bgn) >> 2;   // groups of 4 steps
            for (long q = 0; q < ng; ++q) {
                const float4 A4 = bp[3 * q], B4 = bp[3 * q + 1], C4 = bp[3 * q + 2];
                DSTEP(A4.x, A4.y, A4.z)
                DSTEP(A4.w, B4.x, B4.y)
                DSTEP(B4.z, B4.w, C4.x)
                DSTEP(C4.y, C4.z, C4.w)
            }
            conv = ex2 || (((hi0 - lo0) < EPS) & ((hi1 - lo1) < EPS) &
                           ((hi2 - lo2) < EPS));
        }
        m0 = 0.5f * (lo0 + hi0); m1 = 0.5f * (lo1 + hi1); m2 = 0.5f * (lo2 + hi2);
    }

    // ---- main chunk: 8 steps from registers, 2 float4 stores ----
    float4* op = reinterpret_cast<float4*>(out + start);
    {
        float p0, p1, p2, p3;
        MS(p0, fx[0],  fx[1],  fx[2]);
        MS(p1, fx[3],  fx[4],  fx[5]);
        MS(p2, fx[6],  fx[7],  fx[8]);
        MS(p3, fx[9],  fx[10], fx[11]);
        op[0] = make_float4(p0, p1, p2, p3);
        MS(p0, fx[12], fx[13], fx[14]);
        MS(p1, fx[15], fx[16], fx[17]);
        MS(p2, fx[18], fx[19], fx[20]);
        MS(p3, fx[21], fx[22], fx[23]);
        op[1] = make_float4(p0, p1, p2, p3);
    }
}

extern "C" void kernel_launch(void* const* d_in, const int* in_sizes, int n_in,
                              void* d_out, int out_size, void* d_ws, size_t ws_size,
                              hipStream_t stream) {
    const float* x   = (const float*)d_in[0];   // (B,1,3)
    const float* W   = (const float*)d_in[1];   // (3,3)
    const float* bv  = (const float*)d_in[2];   // (3,)
    const float* n0v = (const float*)d_in[3];   // (3,1)
    float*       out = (float*)d_out;           // (B,1)
    Updater_65395172049297_kernel<<<GRID, BLOCK, 0, stream>>>(x, W, bv, n0v, out);
}

// Round 4
// 108.279 us; speedup vs baseline: 1.5874x; 1.5874x over previous
//
#include <hip/hip_runtime.h>

// Updater: B=4194304 sequential scan, 3 independent scalar recurrences
//   net' = sigmoid(10*(net + u - 0.5)), u = W*x + b, pred = x . net'
// Chunked-scan parallelization with certified warm-up (monotone map ->
// trajectories from 0 and 1 bracket the truth; dual-trajectory warm-up with
// wave-uniform early exit; geometric global backoff, rare, exact at net0).
//
// R4. Counter evidence so far: R3 spilled fx[] (FETCH 180MB + WRITE 114MB
// = 294MB at 3.0 TB/s = 99us, exactly memory-bound on spill traffic);
// R2 was memory-bound too (66MB unique at only 2.1 TB/s: per-lane 96B
// strided gathers, 4 waves/SIMD). The problem is pure memory orchestration:
// move ONLY the unique 66MB, coalesced, with enough waves in flight.
//  - Coalesced float4 block staging into LDS (R0's pattern), but CHUNK=8:
//    window (2048+32)*3 floats ~= 25KB -> 6 blocks/CU = 24 waves/CU
//    (R0 had 12 and a 49.5KB footprint).
//  - LDS padded +1 float4 per 24 slots (per 96 floats): kills the 16-way
//    bank conflict of the 24-float/lane read stride (lanes t,t+4 shift by
//    4 banks -> 2-way = free). 3-float warm reads never cross a pad
//    (24t+3s mod 96 <= 93). Pad offset = ((8t+s)>>5)<<2.
//  - No fx[] registers, no bpermute, no wbuf: warm AND main read LDS.
//    Live set ~40 VGPR; __launch_bounds__(256,6) (cap 85) -> NO SPILLS.
//  - block0/wave0 exact-start handled by rolled global path (1 wave/grid).

#if __has_builtin(__builtin_amdgcn_exp2f)
#define EXP2F(v) __builtin_amdgcn_exp2f(v)
#else
#define EXP2F(v) __expf(0.6931471805599453f * (v))
#endif

namespace {
constexpr int   BTOT   = 4194304;
constexpr int   CHUNK  = 8;                   // output steps per thread
constexpr int   BLOCK  = 256;
constexpr int   BSTEPS = BLOCK * CHUNK;       // 2048 steps per block
constexpr int   WARM   = 32;                  // warm-up window (steps)
constexpr int   GRID   = BTOT / BSTEPS;       // 2048 blocks
constexpr int   NSLOT  = (BSTEPS + WARM) * 3 / 4;        // 1560 float4 slots
constexpr int   LDSW   = 4 * NSLOT + 4 * (NSLOT / 24);   // 6500 floats (26 KB)
constexpr float KEXP   = -14.426950408889634f; // -10 * log2(e)
constexpr float EPS    = 1e-5f;
}

// padded LDS addressing: float4 slot i -> word 4i + 4*(i/24)
#define LDS4R(I_) (*reinterpret_cast<const float4*>(&lds[4 * (I_) + (((I_) / 24) << 2)]))
#define LDS4W(I_, V_) (*reinterpret_cast<float4*>(&lds[4 * (I_) + (((I_) / 24) << 2)]) = (V_))

// sigmoid(10*(n+u-0.5)) = rcp(1 + exp2(KEXP*n + c)), c = (KEXP*W)x + KEXP*(b-.5)
#define CVALS(X0_, X1_, X2_)                                                   \
  const float c0 = fmaf(kw00, (X0_), fmaf(kw01, (X1_), fmaf(kw02, (X2_), kb0))); \
  const float c1 = fmaf(kw10, (X0_), fmaf(kw11, (X1_), fmaf(kw12, (X2_), kb1))); \
  const float c2 = fmaf(kw20, (X0_), fmaf(kw21, (X1_), fmaf(kw22, (X2_), kb2)));

#define SIG(N, C) __builtin_amdgcn_rcpf(1.0f + EXP2F(fmaf(KEXP, (N), (C))))

// warm-step x fetch from padded LDS. F = 24t+3s, pad = 4*((8t+s)>>5)
#define WX(S_, X0_, X1_, X2_)                                                  \
  {                                                                            \
    const int F_ = fb + 3 * (S_) + (((t8 + (S_)) >> 5) << 2);                  \
    X0_ = lds[F_]; X1_ = lds[F_ + 1]; X2_ = lds[F_ + 2];                       \
  }

// dual-trajectory (bracket) step
#define DSTEP(X0_, X1_, X2_)                                                   \
  {                                                                            \
    CVALS(X0_, X1_, X2_)                                                       \
    lo0 = SIG(lo0, c0); hi0 = SIG(hi0, c0);                                    \
    lo1 = SIG(lo1, c1); hi1 = SIG(hi1, c1);                                    \
    lo2 = SIG(lo2, c2); hi2 = SIG(hi2, c2);                                    \
  }

// single-trajectory step
#define SSTEP(X0_, X1_, X2_)                                                   \
  {                                                                            \
    CVALS(X0_, X1_, X2_)                                                       \
    m0 = SIG(m0, c0); m1 = SIG(m1, c1); m2 = SIG(m2, c2);                      \
  }

// warm batch: 4 steps, LDS fetches hoisted above the wave-uniform branch
#define WBATCH(B_)                                                             \
  {                                                                            \
    float X00,X01,X02,X10,X11,X12,X20,X21,X22,X30,X31,X32;                     \
    WX(4*(B_)+0, X00, X01, X02)                                                \
    WX(4*(B_)+1, X10, X11, X12)                                                \
    WX(4*(B_)+2, X20, X21, X22)                                                \
    WX(4*(B_)+3, X30, X31, X32)                                                \
    if (!single) {                                                             \
      DSTEP(X00, X01, X02) DSTEP(X10, X11, X12)                                \
      DSTEP(X20, X21, X22) DSTEP(X30, X31, X32)                                \
      conv = ((hi0 - lo0) < EPS) & ((hi1 - lo1) < EPS) & ((hi2 - lo2) < EPS);  \
      if (__all(conv)) {                                                       \
        m0 = 0.5f * (lo0 + hi0); m1 = 0.5f * (lo1 + hi1);                      \
        m2 = 0.5f * (lo2 + hi2);                                               \
        single = true;                                                         \
      }                                                                        \
    } else {                                                                   \
      SSTEP(X00, X01, X02) SSTEP(X10, X11, X12)                                \
      SSTEP(X20, X21, X22) SSTEP(X30, X31, X32)                                \
    }                                                                          \
  }

// main step: advance + pred
#define MS(P_, X0_, X1_, X2_)                                                  \
  {                                                                            \
    CVALS(X0_, X1_, X2_)                                                       \
    m0 = SIG(m0, c0); m1 = SIG(m1, c1); m2 = SIG(m2, c2);                      \
    P_ = fmaf((X0_), m0, fmaf((X1_), m1, (X2_) * m2));                         \
  }

__global__ __launch_bounds__(BLOCK, 6) void Updater_65395172049297_kernel(
    const float* __restrict__ x, const float* __restrict__ W,
    const float* __restrict__ bv, const float* __restrict__ n0v,
    float* __restrict__ out)
{
    __shared__ float lds[LDSW];

    const float kw00 = KEXP * W[0], kw01 = KEXP * W[1], kw02 = KEXP * W[2];
    const float kw10 = KEXP * W[3], kw11 = KEXP * W[4], kw12 = KEXP * W[5];
    const float kw20 = KEXP * W[6], kw21 = KEXP * W[7], kw22 = KEXP * W[8];
    const float kb0 = KEXP * (bv[0] - 0.5f);
    const float kb1 = KEXP * (bv[1] - 0.5f);
    const float kb2 = KEXP * (bv[2] - 0.5f);
    const float n00 = n0v[0], n01 = n0v[1], n02 = n0v[2];

    const int  t     = threadIdx.x;
    const long S     = (long)blockIdx.x * BSTEPS;
    const long start = S + (long)t * CHUNK;

    // ---- coalesced stage: block window [S-32, S+2048) into padded LDS ----
    if (blockIdx.x == 0) {
        // steps [0,2048) -> local slots 24.. ; slots 0..23 unread (special wave)
        const float4* src = reinterpret_cast<const float4*>(x);
        for (int i = t; i < NSLOT - 24; i += BLOCK) LDS4W(i + 24, src[i]);
    } else {
        const float4* src = reinterpret_cast<const float4*>(x + 3 * (S - WARM));
        for (int i = t; i < NSLOT; i += BLOCK) LDS4W(i, src[i]);
    }
    __syncthreads();

    const int fb = 24 * t;   // thread's warm base float (unpadded)
    const int t8 = 8 * t;

    const bool exact   = (start <= (long)WARM);          // block0/wave0 lanes 0..4
    const int  smin    = exact ? (int)(WARM - (int)start) : 0;
    const bool special = (blockIdx.x == 0) && (t < 64);

    float lo0, lo1, lo2, hi0, hi1, hi2;
    if (exact) { lo0 = hi0 = n00; lo1 = hi1 = n01; lo2 = hi2 = n02; }
    else       { lo0 = lo1 = lo2 = 0.0f; hi0 = hi1 = hi2 = 1.0f; }

    bool  conv = false, single = false;
    float m0 = n00, m1 = n01, m2 = n02;

    if (special) {
        // ONE wave in the grid: rolled warm-up straight from global x.
        for (int s = 0; s < WARM; ++s) {
            if (s >= smin) {
                const long as_ = start - WARM + s;   // >= 0 when s >= smin
                const float X0 = x[3 * as_], X1 = x[3 * as_ + 1], X2 = x[3 * as_ + 2];
                DSTEP(X0, X1, X2)
            }
        }
        conv = ((hi0 - lo0) < EPS) & ((hi1 - lo1) < EPS) & ((hi2 - lo2) < EPS);
        if (__all(conv)) {
            m0 = 0.5f * (lo0 + hi0); m1 = 0.5f * (lo1 + hi1); m2 = 0.5f * (lo2 + hi2);
            single = true;
        }
    } else {
        WBATCH(0) WBATCH(1) WBATCH(2) WBATCH(3)
        WBATCH(4) WBATCH(5) WBATCH(6) WBATCH(7)
    }

    if (!single) {
        // rare certified backoff: extend window 4x per attempt (global x)
        for (int at = 1; at < 10 && !conv; ++at) {
            long wl2 = (long)WARM << (2 * at);
            long bgn = start - wl2;
            bool ex2 = (bgn <= 0);
            if (ex2) bgn = 0;
            if (ex2) { lo0 = hi0 = n00; lo1 = hi1 = n01; lo2 = hi2 = n02; }
            else     { lo0 = lo1 = lo2 = 0.0f; hi0 = hi1 = hi2 = 1.0f; }
            const float4* bp = reinterpret_cast<const float4*>(x + 3 * bgn);
            const long ng = (start - bgn) >> 2;   // groups of 4 steps
            for (long q = 0; q < ng; ++q) {
                const float4 A4 = bp[3 * q], B4 = bp[3 * q + 1], C4 = bp[3 * q + 2];
                DSTEP(A4.x, A4.y, A4.z)
                DSTEP(A4.w, B4.x, B4.y)
                DSTEP(B4.z, B4.w, C4.x)
                DSTEP(C4.y, C4.z, C4.w)
            }
            conv = ex2 || (((hi0 - lo0) < EPS) & ((hi1 - lo1) < EPS) &
                           ((hi2 - lo2) < EPS));
        }
        m0 = 0.5f * (lo0 + hi0); m1 = 0.5f * (lo1 + hi1); m2 = 0.5f * (lo2 + hi2);
    }

    // ---- main chunk: 8 steps, x from padded LDS (slots 6t+24 .. 6t+29) ----
    const int im = 6 * t + 24;
    float4* op = reinterpret_cast<float4*>(out + start);
    {
        float4 A = LDS4R(im + 0), B4 = LDS4R(im + 1), C4 = LDS4R(im + 2);
        float p0, p1, p2, p3;
        MS(p0, A.x,  A.y,  A.z);
        MS(p1, A.w,  B4.x, B4.y);
        MS(p2, B4.z, B4.w, C4.x);
        MS(p3, C4.y, C4.z, C4.w);
        op[0] = make_float4(p0, p1, p2, p3);
        A = LDS4R(im + 3); B4 = LDS4R(im + 4); C4 = LDS4R(im + 5);
        MS(p0, A.x,  A.y,  A.z);
        MS(p1, A.w,  B4.x, B4.y);
        MS(p2, B4.z, B4.w, C4.x);
        MS(p3, C4.y, C4.z, C4.w);
        op[1] = make_float4(p0, p1, p2, p3);
    }
}

extern "C" void kernel_launch(void* const* d_in, const int* in_sizes, int n_in,
                              void* d_out, int out_size, void* d_ws, size_t ws_size,
                              hipStream_t stream) {
    const float* x   = (const float*)d_in[0];   // (B,1,3)
    const float* W   = (const float*)d_in[1];   // (3,3)
    const float* bv  = (const float*)d_in[2];   // (3,)
    const float* n0v = (const float*)d_in[3];   // (3,1)
    float*       out = (float*)d_out;           // (B,1)
    Updater_65395172049297_kernel<<<GRID, BLOCK, 0, stream>>>(x, W, bv, n0v, out);
}

// Round 5
// 107.122 us; speedup vs baseline: 1.6046x; 1.0108x over previous
//
#include <hip/hip_runtime.h>

// Updater: B=4194304 sequential scan, 3 independent scalar recurrences
//   net' = sigmoid(10*(net + u - 0.5)), u = W*x + b, pred = x . net'
// Chunked-scan parallelization with certified warm-up (monotone map ->
// trajectories from 0 and 1 bracket the truth; dual-trajectory warm-up with
// wave-uniform early exit; geometric global backoff, rare, exact at net0).
//
// R5. R4 post-mortem: kernel ~36us. Two errors: (a) warm reads were scalar
// ds_read_b32 at 24-word lane stride; the +4-word/group pad gave 8-way bank
// conflicts (2.94x) -> ~20us of LDS array time/CU; (b) CHUNK=8 doubles
// warm-VALU per output vs CHUNK=16 (13.3us vs 7.8us issue/SIMD).
// This round kills (a) completely:
//  - LDS layout: float4 slot i at word 4i + 4*(i/6) (16B pad per 6 slots).
//    Per-thread base = word 28t (112B aligned); ALL 30 reads are
//    ds_read_b128 with compile-time immediate offsets (warm groups at words
//    0,12,28,40,56,68,84,96; main at 112,124).
//    Bank check: 28t mod 32 has period 8 -> each 16-lane quarter-wave hits
//    all 8 bank-quads x2 lanes = 2-way = free. LDS term ~20us -> ~3us.
//  - Warm stays 4-steps-per-group, loads hoisted above the wave-uniform
//    dual/single branch.
//  - LDS 29.1KB -> 5 blocks/CU, async backfill; __launch_bounds__(256,5)
//    (VGPR cap 102, live ~50, no spills -- R3's spill lesson).
// Expected: kernel ~17-21us (VALU 13.3 || HBM 11 || LDS 3).

#if __has_builtin(__builtin_amdgcn_exp2f)
#define EXP2F(v) __builtin_amdgcn_exp2f(v)
#else
#define EXP2F(v) __expf(0.6931471805599453f * (v))
#endif

namespace {
constexpr int   BTOT   = 4194304;
constexpr int   CHUNK  = 8;                   // output steps per thread
constexpr int   BLOCK  = 256;
constexpr int   BSTEPS = BLOCK * CHUNK;       // 2048 steps per block
constexpr int   WARM   = 32;                  // warm-up window (steps)
constexpr int   GRID   = BTOT / BSTEPS;       // 2048 blocks
constexpr int   NSLOT  = (BSTEPS + WARM) * 3 / 4;   // 1560 float4 slots
constexpr int   LDSW   = 4 * NSLOT + 4 * (NSLOT / 6); // 7280 words = 29120 B
constexpr float KEXP   = -14.426950408889634f; // -10 * log2(e)
constexpr float EPS    = 1e-5f;
}

// padded LDS word address for float4 slot i
#define SLOTW(I_) (4 * (I_) + (((I_) / 6) << 2))

// sigmoid(10*(n+u-0.5)) = rcp(1 + exp2(KEXP*n + c)), c = (KEXP*W)x + KEXP*(b-.5)
#define CVALS(X0_, X1_, X2_)                                                   \
  const float c0 = fmaf(kw00, (X0_), fmaf(kw01, (X1_), fmaf(kw02, (X2_), kb0))); \
  const float c1 = fmaf(kw10, (X0_), fmaf(kw11, (X1_), fmaf(kw12, (X2_), kb1))); \
  const float c2 = fmaf(kw20, (X0_), fmaf(kw21, (X1_), fmaf(kw22, (X2_), kb2)));

#define SIG(N, C) __builtin_amdgcn_rcpf(1.0f + EXP2F(fmaf(KEXP, (N), (C))))

// dual-trajectory (bracket) step
#define DSTEP(X0_, X1_, X2_)                                                   \
  {                                                                            \
    CVALS(X0_, X1_, X2_)                                                       \
    lo0 = SIG(lo0, c0); hi0 = SIG(hi0, c0);                                    \
    lo1 = SIG(lo1, c1); hi1 = SIG(hi1, c1);                                    \
    lo2 = SIG(lo2, c2); hi2 = SIG(hi2, c2);                                    \
  }

// single-trajectory step
#define SSTEP(X0_, X1_, X2_)                                                   \
  {                                                                            \
    CVALS(X0_, X1_, X2_)                                                       \
    m0 = SIG(m0, c0); m1 = SIG(m1, c1); m2 = SIG(m2, c2);                      \
  }

// 3 x ds_read_b128 at compile-time offsets from per-thread base tb
#define LDG3(W0_)                                                              \
  const float4 A4_ = *reinterpret_cast<const float4*>(tb + (W0_));             \
  const float4 B4_ = *reinterpret_cast<const float4*>(tb + (W0_) + 4);         \
  const float4 C4_ = *reinterpret_cast<const float4*>(tb + (W0_) + 8);

// warm batch: 4 steps; loads hoisted above the wave-uniform branch
#define WBATCH(W0_)                                                            \
  {                                                                            \
    LDG3(W0_)                                                                  \
    if (!single) {                                                             \
      DSTEP(A4_.x, A4_.y, A4_.z) DSTEP(A4_.w, B4_.x, B4_.y)                    \
      DSTEP(B4_.z, B4_.w, C4_.x) DSTEP(C4_.y, C4_.z, C4_.w)                    \
      conv = ((hi0 - lo0) < EPS) & ((hi1 - lo1) < EPS) & ((hi2 - lo2) < EPS);  \
      if (__all(conv)) {                                                       \
        m0 = 0.5f * (lo0 + hi0); m1 = 0.5f * (lo1 + hi1);                      \
        m2 = 0.5f * (lo2 + hi2);                                               \
        single = true;                                                         \
      }                                                                        \
    } else {                                                                   \
      SSTEP(A4_.x, A4_.y, A4_.z) SSTEP(A4_.w, B4_.x, B4_.y)                    \
      SSTEP(B4_.z, B4_.w, C4_.x) SSTEP(C4_.y, C4_.z, C4_.w)                    \
    }                                                                          \
  }

// main step: advance + pred
#define MS(P_, X0_, X1_, X2_)                                                  \
  {                                                                            \
    CVALS(X0_, X1_, X2_)                                                       \
    m0 = SIG(m0, c0); m1 = SIG(m1, c1); m2 = SIG(m2, c2);                      \
    P_ = fmaf((X0_), m0, fmaf((X1_), m1, (X2_) * m2));                         \
  }

__global__ __launch_bounds__(BLOCK, 5) void Updater_65395172049297_kernel(
    const float* __restrict__ x, const float* __restrict__ W,
    const float* __restrict__ bv, const float* __restrict__ n0v,
    float* __restrict__ out)
{
    __shared__ float lds[LDSW];

    const float kw00 = KEXP * W[0], kw01 = KEXP * W[1], kw02 = KEXP * W[2];
    const float kw10 = KEXP * W[3], kw11 = KEXP * W[4], kw12 = KEXP * W[5];
    const float kw20 = KEXP * W[6], kw21 = KEXP * W[7], kw22 = KEXP * W[8];
    const float kb0 = KEXP * (bv[0] - 0.5f);
    const float kb1 = KEXP * (bv[1] - 0.5f);
    const float kb2 = KEXP * (bv[2] - 0.5f);
    const float n00 = n0v[0], n01 = n0v[1], n02 = n0v[2];

    const int  t     = threadIdx.x;
    const long S     = (long)blockIdx.x * BSTEPS;
    const long start = S + (long)t * CHUNK;

    // ---- coalesced stage: block window [S-32, S+2048) into padded LDS ----
    if (blockIdx.x == 0) {
        // step s -> window offset s+32 -> slot (3s+96)/4 = i+24 for float4 i
        const float4* src = reinterpret_cast<const float4*>(x);
        for (int i = t; i < NSLOT - 24; i += BLOCK) {
            const int sl = i + 24;
            *reinterpret_cast<float4*>(&lds[SLOTW(sl)]) = src[i];
        }
    } else {
        const float4* src = reinterpret_cast<const float4*>(x + 3 * (S - WARM));
        for (int i = t; i < NSLOT; i += BLOCK) {
            *reinterpret_cast<float4*>(&lds[SLOTW(i)]) = src[i];
        }
    }
    __syncthreads();

    // per-thread base: slot 6t -> word 28t (112B aligned); all reads are
    // b128 at compile-time offsets {0,12,28,40,56,68,84,96 | 112,124}
    const float* tb = lds + 28 * t;

    const bool exact   = (start <= (long)WARM);          // block0/wave0 lanes 0..4
    const int  smin    = exact ? (int)(WARM - (int)start) : 0;
    const bool special = (blockIdx.x == 0) && (t < 64);

    float lo0, lo1, lo2, hi0, hi1, hi2;
    if (exact) { lo0 = hi0 = n00; lo1 = hi1 = n01; lo2 = hi2 = n02; }
    else       { lo0 = lo1 = lo2 = 0.0f; hi0 = hi1 = hi2 = 1.0f; }

    bool  conv = false, single = false;
    float m0 = n00, m1 = n01, m2 = n02;

    if (special) {
        // ONE wave in the grid: rolled warm-up straight from global x.
        for (int s = 0; s < WARM; ++s) {
            if (s >= smin) {
                const long as_ = start - WARM + s;   // >= 0 when s >= smin
                const float X0 = x[3 * as_], X1 = x[3 * as_ + 1], X2 = x[3 * as_ + 2];
                DSTEP(X0, X1, X2)
            }
        }
        conv = ((hi0 - lo0) < EPS) & ((hi1 - lo1) < EPS) & ((hi2 - lo2) < EPS);
        if (__all(conv)) {
            m0 = 0.5f * (lo0 + hi0); m1 = 0.5f * (lo1 + hi1); m2 = 0.5f * (lo2 + hi2);
            single = true;
        }
    } else {
        WBATCH(0)  WBATCH(12) WBATCH(28) WBATCH(40)
        WBATCH(56) WBATCH(68) WBATCH(84) WBATCH(96)
    }

    if (!single) {
        // rare certified backoff: extend window 4x per attempt (global x)
        for (int at = 1; at < 10 && !conv; ++at) {
            long wl2 = (long)WARM << (2 * at);
            long bgn = start - wl2;
            bool ex2 = (bgn <= 0);
            if (ex2) bgn = 0;
            if (ex2) { lo0 = hi0 = n00; lo1 = hi1 = n01; lo2 = hi2 = n02; }
            else     { lo0 = lo1 = lo2 = 0.0f; hi0 = hi1 = hi2 = 1.0f; }
            const float4* bp = reinterpret_cast<const float4*>(x + 3 * bgn);
            const long ng = (start - bgn) >> 2;   // groups of 4 steps
            for (long q = 0; q < ng; ++q) {
                const float4 A4 = bp[3 * q], B4 = bp[3 * q + 1], C4 = bp[3 * q + 2];
                DSTEP(A4.x, A4.y, A4.z)
                DSTEP(A4.w, B4.x, B4.y)
                DSTEP(B4.z, B4.w, C4.x)
                DSTEP(C4.y, C4.z, C4.w)
            }
            conv = ex2 || (((hi0 - lo0) < EPS) & ((hi1 - lo1) < EPS) &
                           ((hi2 - lo2) < EPS));
        }
        m0 = 0.5f * (lo0 + hi0); m1 = 0.5f * (lo1 + hi1); m2 = 0.5f * (lo2 + hi2);
    }

    // ---- main chunk: 8 steps, b128 from padded LDS (words 112..132) ----
    float4* op = reinterpret_cast<float4*>(out + start);
    {
        LDG3(112)
        float p0, p1, p2, p3;
        MS(p0, A4_.x, A4_.y, A4_.z);
        MS(p1, A4_.w, B4_.x, B4_.y);
        MS(p2, B4_.z, B4_.w, C4_.x);
        MS(p3, C4_.y, C4_.z, C4_.w);
        op[0] = make_float4(p0, p1, p2, p3);
    }
    {
        LDG3(124)
        float p0, p1, p2, p3;
        MS(p0, A4_.x, A4_.y, A4_.z);
        MS(p1, A4_.w, B4_.x, B4_.y);
        MS(p2, B4_.z, B4_.w, C4_.x);
        MS(p3, C4_.y, C4_.z, C4_.w);
        op[1] = make_float4(p0, p1, p2, p3);
    }
}

extern "C" void kernel_launch(void* const* d_in, const int* in_sizes, int n_in,
                              void* d_out, int out_size, void* d_ws, size_t ws_size,
                              hipStream_t stream) {
    const float* x   = (const float*)d_in[0];   // (B,1,3)
    const float* W   = (const float*)d_in[1];   // (3,3)
    const float* bv  = (const float*)d_in[2];   // (3,)
    const float* n0v = (const float*)d_in[3];   // (3,1)
    float*       out = (float*)d_out;           // (B,1)
    Updater_65395172049297_kernel<<<GRID, BLOCK, 0, stream>>>(x, W, bv, n0v, out);
}

// Round 6
// 99.694 us; speedup vs baseline: 1.7241x; 1.0745x over previous
//
#include <hip/hip_runtime.h>

// Updater: B=4194304 sequential scan, 3 independent scalar recurrences
//   net' = sigmoid(10*(net + u - 0.5)), u = W*x + b, pred = x . net'
// Chunked-scan parallelization with certified warm-up (monotone map ->
// trajectories from 0 and 1 bracket the truth; dual-trajectory warm-up with
// wave-uniform early exit; geometric global backoff, rare, exact at net0).
//
// R6. Cross-round model: time ~= warm-issue + ~18us serial/latency residue.
// Memory-layout fixes (R4/R5) moved ~1us; CHUNK8->16 moved 4-5us = exactly
// the warm-issue delta. So: CHUNK=32 (warm trans per output 27->9 vs CHUNK8).
//  - Thread's warm window == lane-1's main chunk -> warm x via ONE
//    constant-distance bpermute per value. No block staging, no big LDS,
//    no block-wide stage->sync serial phase (only a 2KB boundary buffer).
//  - Main x in registers: fx[96] from 24 contiguous dwordx4 per thread
//    (each 64B line consumed by exactly one thread -> unique ~50MB fetch,
//    proven in R2). Wave gather footprint 24KB, L1-resident.
//  - __launch_bounds__(256,2): 256-VGPR cap, fx[96] cannot spill (R3's
//    spill was the over-tight bound, not the array).
//  - Grid 512 blocks = 2048 waves = 2/SIMD: thin, but issue/step (138cy)
//    >> chain latency (36cy), so waves are self-sufficient.

#if __has_builtin(__builtin_amdgcn_exp2f)
#define EXP2F(v) __builtin_amdgcn_exp2f(v)
#else
#define EXP2F(v) __expf(0.6931471805599453f * (v))
#endif

namespace {
constexpr int   BTOT   = 4194304;
constexpr int   CHUNK  = 32;                  // output steps per thread
constexpr int   BLOCK  = 256;
constexpr int   BSTEPS = BLOCK * CHUNK;       // 8192 steps per block
constexpr int   WARM   = 32;                  // warm-up window (steps)
constexpr int   GRID   = BTOT / BSTEPS;       // 512 blocks
constexpr float KEXP   = -14.426950408889634f; // -10 * log2(e)
constexpr float EPS    = 1e-5f;
}

// sigmoid(10*(n+u-0.5)) = rcp(1 + exp2(KEXP*n + c)), c = (KEXP*W)x + KEXP*(b-.5)
#define CVALS(X0_, X1_, X2_)                                                   \
  const float c0 = fmaf(kw00, (X0_), fmaf(kw01, (X1_), fmaf(kw02, (X2_), kb0))); \
  const float c1 = fmaf(kw10, (X0_), fmaf(kw11, (X1_), fmaf(kw12, (X2_), kb1))); \
  const float c2 = fmaf(kw20, (X0_), fmaf(kw21, (X1_), fmaf(kw22, (X2_), kb2)));

#define SIG(N, C) __builtin_amdgcn_rcpf(1.0f + EXP2F(fmaf(KEXP, (N), (C))))

// pull lane-1's register (addr a1 precomputed); lane 0 overridden via wbuf
#define PULL(VAL_) \
  __int_as_float(__builtin_amdgcn_ds_bpermute(a1, __float_as_int(VAL_)))

// warm-step S_ (compile-time): x = lane-1's fx[3S..3S+2]; lane0 from wbuf
#define FETCH1(S_, XD0, XD1, XD2)                                              \
  XD0 = PULL(fx[3 * (S_) + 0]);                                                \
  XD1 = PULL(fx[3 * (S_) + 1]);                                                \
  XD2 = PULL(fx[3 * (S_) + 2]);                                                \
  if (lane == 0) {                                                             \
    const float4 wv_ = wbuf[w][(S_)];                                          \
    XD0 = wv_.x; XD1 = wv_.y; XD2 = wv_.z;                                     \
  }

// dual-trajectory (bracket) step
#define DSTEP(X0_, X1_, X2_)                                                   \
  {                                                                            \
    CVALS(X0_, X1_, X2_)                                                       \
    lo0 = SIG(lo0, c0); hi0 = SIG(hi0, c0);                                    \
    lo1 = SIG(lo1, c1); hi1 = SIG(hi1, c1);                                    \
    lo2 = SIG(lo2, c2); hi2 = SIG(hi2, c2);                                    \
  }

// single-trajectory step
#define SSTEP(X0_, X1_, X2_)                                                   \
  {                                                                            \
    CVALS(X0_, X1_, X2_)                                                       \
    m0 = SIG(m0, c0); m1 = SIG(m1, c1); m2 = SIG(m2, c2);                      \
  }

// warm batch: 4 steps; fetches hoisted above the wave-uniform branch
#define WBATCH(B_)                                                             \
  {                                                                            \
    float X00,X01,X02,X10,X11,X12,X20,X21,X22,X30,X31,X32;                     \
    FETCH1(4*(B_)+0, X00, X01, X02)                                            \
    FETCH1(4*(B_)+1, X10, X11, X12)                                            \
    FETCH1(4*(B_)+2, X20, X21, X22)                                            \
    FETCH1(4*(B_)+3, X30, X31, X32)                                            \
    if (!single) {                                                             \
      DSTEP(X00, X01, X02) DSTEP(X10, X11, X12)                                \
      DSTEP(X20, X21, X22) DSTEP(X30, X31, X32)                                \
      conv = ((hi0 - lo0) < EPS) & ((hi1 - lo1) < EPS) & ((hi2 - lo2) < EPS);  \
      if (__all(conv)) {                                                       \
        m0 = 0.5f * (lo0 + hi0); m1 = 0.5f * (lo1 + hi1);                      \
        m2 = 0.5f * (lo2 + hi2);                                               \
        single = true;                                                         \
      }                                                                        \
    } else {                                                                   \
      SSTEP(X00, X01, X02) SSTEP(X10, X11, X12)                                \
      SSTEP(X20, X21, X22) SSTEP(X30, X31, X32)                                \
    }                                                                          \
  }

// main step: advance + pred (x from registers)
#define MS(P_, X0_, X1_, X2_)                                                  \
  {                                                                            \
    CVALS(X0_, X1_, X2_)                                                       \
    m0 = SIG(m0, c0); m1 = SIG(m1, c1); m2 = SIG(m2, c2);                      \
    P_ = fmaf((X0_), m0, fmaf((X1_), m1, (X2_) * m2));                         \
  }

__global__ __launch_bounds__(BLOCK, 2) void Updater_65395172049297_kernel(
    const float* __restrict__ x, const float* __restrict__ W,
    const float* __restrict__ bv, const float* __restrict__ n0v,
    float* __restrict__ out)
{
    __shared__ float4 wbuf[BLOCK / 64][WARM];   // 4 waves x 32 steps = 2KB

    const float kw00 = KEXP * W[0], kw01 = KEXP * W[1], kw02 = KEXP * W[2];
    const float kw10 = KEXP * W[3], kw11 = KEXP * W[4], kw12 = KEXP * W[5];
    const float kw20 = KEXP * W[6], kw21 = KEXP * W[7], kw22 = KEXP * W[8];
    const float kb0 = KEXP * (bv[0] - 0.5f);
    const float kb1 = KEXP * (bv[1] - 0.5f);
    const float kb2 = KEXP * (bv[2] - 0.5f);
    const float n00 = n0v[0], n01 = n0v[1], n02 = n0v[2];

    const int  lane  = threadIdx.x & 63;
    const int  w     = threadIdx.x >> 6;
    const long S     = (long)blockIdx.x * BSTEPS;
    const long start = S + (long)threadIdx.x * CHUNK;
    const int  a1    = ((lane >= 1) ? (lane - 1) : 0) << 2;

    // ---- one-shot gather: this thread's 32-step x chunk into registers ----
    float fx[96];
    {
        const float4* mp = reinterpret_cast<const float4*>(x + 3 * start);
#pragma unroll
        for (int i = 0; i < 24; ++i) {
            const float4 v = mp[i];
            fx[4 * i + 0] = v.x; fx[4 * i + 1] = v.y;
            fx[4 * i + 2] = v.z; fx[4 * i + 3] = v.w;
        }
    }

    // ---- stage per-wave boundary window (32 steps before wave start) ----
    {
        const long wbase = S + (long)w * (64 * CHUNK);
        if (lane < WARM) {
            long sstep = wbase - WARM + lane;
            if (sstep < 0) sstep = 0;   // block0/wave0: never consumed (special)
            const float* xp = x + 3 * sstep;
            wbuf[w][lane] = make_float4(xp[0], xp[1], xp[2], 0.0f);
        }
    }
    __syncthreads();

    const bool exact   = (start <= (long)WARM);          // block0/wave0 lanes 0,1
    const int  smin    = exact ? (int)(WARM - (int)start) : 0;
    const bool special = (blockIdx.x == 0) && (w == 0);

    float lo0, lo1, lo2, hi0, hi1, hi2;
    if (exact) { lo0 = hi0 = n00; lo1 = hi1 = n01; lo2 = hi2 = n02; }
    else       { lo0 = lo1 = lo2 = 0.0f; hi0 = hi1 = hi2 = 1.0f; }

    bool  conv = false, single = false;
    float m0 = n00, m1 = n01, m2 = n02;

    if (special) {
        // ONE wave in the grid: rolled warm-up straight from global x.
        for (int s = 0; s < WARM; ++s) {
            if (s >= smin) {
                const long as_ = start - WARM + s;   // >= 0 when s >= smin
                const float X0 = x[3 * as_], X1 = x[3 * as_ + 1], X2 = x[3 * as_ + 2];
                DSTEP(X0, X1, X2)
            }
        }
        conv = ((hi0 - lo0) < EPS) & ((hi1 - lo1) < EPS) & ((hi2 - lo2) < EPS);
        if (__all(conv)) {
            m0 = 0.5f * (lo0 + hi0); m1 = 0.5f * (lo1 + hi1); m2 = 0.5f * (lo2 + hi2);
            single = true;
        }
    } else {
        WBATCH(0) WBATCH(1) WBATCH(2) WBATCH(3)
        WBATCH(4) WBATCH(5) WBATCH(6) WBATCH(7)
    }

    if (!single) {
        // rare certified backoff: extend window 4x per attempt (global x)
        for (int at = 1; at < 10 && !conv; ++at) {
            long wl2 = (long)WARM << (2 * at);
            long bgn = start - wl2;
            bool ex2 = (bgn <= 0);
            if (ex2) bgn = 0;
            if (ex2) { lo0 = hi0 = n00; lo1 = hi1 = n01; lo2 = hi2 = n02; }
            else     { lo0 = lo1 = lo2 = 0.0f; hi0 = hi1 = hi2 = 1.0f; }
            const float4* bp = reinterpret_cast<const float4*>(x + 3 * bgn);
            const long ng = (start - bgn) >> 2;   // groups of 4 steps
            for (long q = 0; q < ng; ++q) {
                const float4 A4 = bp[3 * q], B4 = bp[3 * q + 1], C4 = bp[3 * q + 2];
                DSTEP(A4.x, A4.y, A4.z)
                DSTEP(A4.w, B4.x, B4.y)
                DSTEP(B4.z, B4.w, C4.x)
                DSTEP(C4.y, C4.z, C4.w)
            }
            conv = ex2 || (((hi0 - lo0) < EPS) & ((hi1 - lo1) < EPS) &
                           ((hi2 - lo2) < EPS));
        }
        m0 = 0.5f * (lo0 + hi0); m1 = 0.5f * (lo1 + hi1); m2 = 0.5f * (lo2 + hi2);
    }

    // ---- main chunk: 32 steps from registers, 8 float4 stores ----
    float4* op = reinterpret_cast<float4*>(out + start);
#pragma unroll
    for (int q = 0; q < 8; ++q) {
        float p0, p1, p2, p3;
        MS(p0, fx[12 * q + 0], fx[12 * q + 1],  fx[12 * q + 2]);
        MS(p1, fx[12 * q + 3], fx[12 * q + 4],  fx[12 * q + 5]);
        MS(p2, fx[12 * q + 6], fx[12 * q + 7],  fx[12 * q + 8]);
        MS(p3, fx[12 * q + 9], fx[12 * q + 10], fx[12 * q + 11]);
        op[q] = make_float4(p0, p1, p2, p3);
    }
}

extern "C" void kernel_launch(void* const* d_in, const int* in_sizes, int n_in,
                              void* d_out, int out_size, void* d_ws, size_t ws_size,
                              hipStream_t stream) {
    const float* x   = (const float*)d_in[0];   // (B,1,3)
    const float* W   = (const float*)d_in[1];   // (3,3)
    const float* bv  = (const float*)d_in[2];   // (3,)
    const float* n0v = (const float*)d_in[3];   // (3,1)
    float*       out = (float*)d_out;           // (B,1)
    Updater_65395172049297_kernel<<<GRID, BLOCK, 0, stream>>>(x, W, bv, n0v, out);
}

// Round 7
// 99.575 us; speedup vs baseline: 1.7262x; 1.0012x over previous
//
#include <hip/hip_runtime.h>

// Updater: B=4194304 sequential scan, 3 independent scalar recurrences
//   net' = sigmoid(10*(net + u - 0.5)), u = W*x + b, pred = x . net'
// Chunked-scan parallelization with certified warm-up (monotone map ->
// trajectories from 0 and 1 bracket the truth; dual-trajectory warm-up with
// wave-uniform early exit; geometric global backoff, rare, exact at net0).
//
// R7 vs R6 (~27.7us kernel). Cross-round model: issue+HBM ~= 11-15us, so
// ~13us is serial-phase/straggler residue. Three structural serializers
// removed this round:
//  - __syncthreads DELETED: wbuf[w] is wave-private (written+read only by
//    wave w); same-wave cross-lane LDS needs only lgkmcnt (lockstep wave),
//    no barrier. The barrier forced a vmcnt(0) drain of all 24 gather
//    loads for every wave before ANY warm could start.
//  - Special block0/wave0 path DELETED (was 32 rolled scalar global
//    load+DSTEP iterations = a serial straggler bounding the grid at
//    2 waves/SIMD). Unified: lane1's warm window == lane0's fx (bpermute
//    OK); lane0 (start=0) keeps a width-0 bracket (lo=hi=net0 -> identical
//    updates, conv stays true) and its m is overwritten with net0 at the
//    end. wbuf garbage reads for wave0/lane0 are consumed only by that
//    overwritten trajectory.
//  - Staging order: wbuf global load issued BEFORE the 24-load gather so
//    its LDS write (and lane0's reads) don't queue behind the gather.
// Everything else (CHUNK=32, fx[96] register gather = unique ~50MB fetch,
// one constant-distance bpermute warm, __launch_bounds__(256,2) so fx
// cannot spill, certified backoff) carried from R6.

#if __has_builtin(__builtin_amdgcn_exp2f)
#define EXP2F(v) __builtin_amdgcn_exp2f(v)
#else
#define EXP2F(v) __expf(0.6931471805599453f * (v))
#endif

namespace {
constexpr int   BTOT   = 4194304;
constexpr int   CHUNK  = 32;                  // output steps per thread
constexpr int   BLOCK  = 256;
constexpr int   BSTEPS = BLOCK * CHUNK;       // 8192 steps per block
constexpr int   WARM   = 32;                  // warm-up window (steps)
constexpr int   GRID   = BTOT / BSTEPS;       // 512 blocks
constexpr float KEXP   = -14.426950408889634f; // -10 * log2(e)
constexpr float EPS    = 1e-5f;
}

// sigmoid(10*(n+u-0.5)) = rcp(1 + exp2(KEXP*n + c)), c = (KEXP*W)x + KEXP*(b-.5)
#define CVALS(X0_, X1_, X2_)                                                   \
  const float c0 = fmaf(kw00, (X0_), fmaf(kw01, (X1_), fmaf(kw02, (X2_), kb0))); \
  const float c1 = fmaf(kw10, (X0_), fmaf(kw11, (X1_), fmaf(kw12, (X2_), kb1))); \
  const float c2 = fmaf(kw20, (X0_), fmaf(kw21, (X1_), fmaf(kw22, (X2_), kb2)));

#define SIG(N, C) __builtin_amdgcn_rcpf(1.0f + EXP2F(fmaf(KEXP, (N), (C))))

// pull lane-1's register (addr a1 precomputed); lane 0 overridden via wbuf
#define PULL(VAL_) \
  __int_as_float(__builtin_amdgcn_ds_bpermute(a1, __float_as_int(VAL_)))

// warm-step S_ (compile-time): x = lane-1's fx[3S..3S+2]; lane0 from wbuf
#define FETCH1(S_, XD0, XD1, XD2)                                              \
  XD0 = PULL(fx[3 * (S_) + 0]);                                                \
  XD1 = PULL(fx[3 * (S_) + 1]);                                                \
  XD2 = PULL(fx[3 * (S_) + 2]);                                                \
  if (lane == 0) {                                                             \
    const float4 wv_ = wb[(S_)];                                               \
    XD0 = wv_.x; XD1 = wv_.y; XD2 = wv_.z;                                     \
  }

// dual-trajectory (bracket) step
#define DSTEP(X0_, X1_, X2_)                                                   \
  {                                                                            \
    CVALS(X0_, X1_, X2_)                                                       \
    lo0 = SIG(lo0, c0); hi0 = SIG(hi0, c0);                                    \
    lo1 = SIG(lo1, c1); hi1 = SIG(hi1, c1);                                    \
    lo2 = SIG(lo2, c2); hi2 = SIG(hi2, c2);                                    \
  }

// single-trajectory step
#define SSTEP(X0_, X1_, X2_)                                                   \
  {                                                                            \
    CVALS(X0_, X1_, X2_)                                                       \
    m0 = SIG(m0, c0); m1 = SIG(m1, c1); m2 = SIG(m2, c2);                      \
  }

// warm batch: 4 steps; fetches hoisted above the wave-uniform branch
#define WBATCH(B_)                                                             \
  {                                                                            \
    float X00,X01,X02,X10,X11,X12,X20,X21,X22,X30,X31,X32;                     \
    FETCH1(4*(B_)+0, X00, X01, X02)                                            \
    FETCH1(4*(B_)+1, X10, X11, X12)                                            \
    FETCH1(4*(B_)+2, X20, X21, X22)                                            \
    FETCH1(4*(B_)+3, X30, X31, X32)                                            \
    if (!single) {                                                             \
      DSTEP(X00, X01, X02) DSTEP(X10, X11, X12)                                \
      DSTEP(X20, X21, X22) DSTEP(X30, X31, X32)                                \
      conv = ((hi0 - lo0) < EPS) & ((hi1 - lo1) < EPS) & ((hi2 - lo2) < EPS);  \
      if (__all(conv)) {                                                       \
        m0 = 0.5f * (lo0 + hi0); m1 = 0.5f * (lo1 + hi1);                      \
        m2 = 0.5f * (lo2 + hi2);                                               \
        single = true;                                                         \
      }                                                                        \
    } else {                                                                   \
      SSTEP(X00, X01, X02) SSTEP(X10, X11, X12)                                \
      SSTEP(X20, X21, X22) SSTEP(X30, X31, X32)                                \
    }                                                                          \
  }

// main step: advance + pred (x from registers)
#define MS(P_, X0_, X1_, X2_)                                                  \
  {                                                                            \
    CVALS(X0_, X1_, X2_)                                                       \
    m0 = SIG(m0, c0); m1 = SIG(m1, c1); m2 = SIG(m2, c2);                      \
    P_ = fmaf((X0_), m0, fmaf((X1_), m1, (X2_) * m2));                         \
  }

__global__ __launch_bounds__(BLOCK, 2) void Updater_65395172049297_kernel(
    const float* __restrict__ x, const float* __restrict__ W,
    const float* __restrict__ bv, const float* __restrict__ n0v,
    float* __restrict__ out)
{
    __shared__ float4 wbuf[BLOCK / 64][WARM];   // 4 waves x 32 steps = 2KB

    const float kw00 = KEXP * W[0], kw01 = KEXP * W[1], kw02 = KEXP * W[2];
    const float kw10 = KEXP * W[3], kw11 = KEXP * W[4], kw12 = KEXP * W[5];
    const float kw20 = KEXP * W[6], kw21 = KEXP * W[7], kw22 = KEXP * W[8];
    const float kb0 = KEXP * (bv[0] - 0.5f);
    const float kb1 = KEXP * (bv[1] - 0.5f);
    const float kb2 = KEXP * (bv[2] - 0.5f);
    const float n00 = n0v[0], n01 = n0v[1], n02 = n0v[2];

    const int  lane  = threadIdx.x & 63;
    const int  w     = threadIdx.x >> 6;
    const long S     = (long)blockIdx.x * BSTEPS;
    const long start = S + (long)threadIdx.x * CHUNK;
    const int  a1    = ((lane >= 1) ? (lane - 1) : 0) << 2;
    const float4* wb = wbuf[w];

    // ---- per-wave boundary window load FIRST (1 load/lane, lanes<32) ----
    float4 wv;
    {
        const long wbase = S + (long)w * (64 * CHUNK);
        long sstep = wbase - WARM + lane;
        if (sstep < 0) sstep = 0;   // block0/wave0: consumed only by the
                                    // overwritten lane-0 trajectory
        if (lane < WARM) {
            const float* xp = x + 3 * sstep;
            wv = make_float4(xp[0], xp[1], xp[2], 0.0f);
        }
    }

    // ---- one-shot gather: this thread's 32-step x chunk into registers ----
    float fx[96];
    {
        const float4* mp = reinterpret_cast<const float4*>(x + 3 * start);
#pragma unroll
        for (int i = 0; i < 24; ++i) {
            const float4 v = mp[i];
            fx[4 * i + 0] = v.x; fx[4 * i + 1] = v.y;
            fx[4 * i + 2] = v.z; fx[4 * i + 3] = v.w;
        }
    }

    // wave-private LDS write; no __syncthreads needed (same-wave lockstep,
    // compiler inserts the lgkmcnt before lane0's reads)
    if (lane < WARM) wbuf[w][lane] = wv;

    // exact-start lanes: block0/wave0 lanes 0 (start=0) and 1 (start=32).
    // Width-0 bracket -> identical lo/hi updates -> conv stays true; lane0's
    // (garbage-x) trajectory is overwritten with net0 after the warm-up.
    const bool exact = (start <= (long)WARM);
    float lo0, lo1, lo2, hi0, hi1, hi2;
    if (exact) { lo0 = hi0 = n00; lo1 = hi1 = n01; lo2 = hi2 = n02; }
    else       { lo0 = lo1 = lo2 = 0.0f; hi0 = hi1 = hi2 = 1.0f; }

    bool  conv = false, single = false;
    float m0 = n00, m1 = n01, m2 = n02;

    WBATCH(0) WBATCH(1) WBATCH(2) WBATCH(3)
    WBATCH(4) WBATCH(5) WBATCH(6) WBATCH(7)

    if (!single) {
        // rare certified backoff: extend window 4x per attempt (global x)
        for (int at = 1; at < 10 && !conv; ++at) {
            long wl2 = (long)WARM << (2 * at);
            long bgn = start - wl2;
            bool ex2 = (bgn <= 0);
            if (ex2) bgn = 0;
            if (ex2) { lo0 = hi0 = n00; lo1 = hi1 = n01; lo2 = hi2 = n02; }
            else     { lo0 = lo1 = lo2 = 0.0f; hi0 = hi1 = hi2 = 1.0f; }
            const float4* bp = reinterpret_cast<const float4*>(x + 3 * bgn);
            const long ng = (start - bgn) >> 2;   // groups of 4 steps
            for (long q = 0; q < ng; ++q) {
                const float4 A4 = bp[3 * q], B4 = bp[3 * q + 1], C4 = bp[3 * q + 2];
                DSTEP(A4.x, A4.y, A4.z)
                DSTEP(A4.w, B4.x, B4.y)
                DSTEP(B4.z, B4.w, C4.x)
                DSTEP(C4.y, C4.z, C4.w)
            }
            conv = ex2 || (((hi0 - lo0) < EPS) & ((hi1 - lo1) < EPS) &
                           ((hi2 - lo2) < EPS));
        }
        m0 = 0.5f * (lo0 + hi0); m1 = 0.5f * (lo1 + hi1); m2 = 0.5f * (lo2 + hi2);
    }

    // the single thread whose whole warm window is out-of-range: exact net0
    if (start == 0) { m0 = n00; m1 = n01; m2 = n02; }

    // ---- main chunk: 32 steps from registers, 8 float4 stores ----
    float4* op = reinterpret_cast<float4*>(out + start);
#pragma unroll
    for (int q = 0; q < 8; ++q) {
        float p0, p1, p2, p3;
        MS(p0, fx[12 * q + 0], fx[12 * q + 1],  fx[12 * q + 2]);
        MS(p1, fx[12 * q + 3], fx[12 * q + 4],  fx[12 * q + 5]);
        MS(p2, fx[12 * q + 6], fx[12 * q + 7],  fx[12 * q + 8]);
        MS(p3, fx[12 * q + 9], fx[12 * q + 10], fx[12 * q + 11]);
        op[q] = make_float4(p0, p1, p2, p3);
    }
}

extern "C" void kernel_launch(void* const* d_in, const int* in_sizes, int n_in,
                              void* d_out, int out_size, void* d_ws, size_t ws_size,
                              hipStream_t stream) {
    const float* x   = (const float*)d_in[0];   // (B,1,3)
    const float* W   = (const float*)d_in[1];   // (3,3)
    const float* bv  = (const float*)d_in[2];   // (3,)
    const float* n0v = (const float*)d_in[3];   // (3,1)
    float*       out = (float*)d_out;           // (B,1)
    Updater_65395172049297_kernel<<<GRID, BLOCK, 0, stream>>>(x, W, bv, n0v, out);
}